// Round 1
// baseline (2286.287 us; speedup 1.0000x reference)
//
#include <hip/hip_runtime.h>
#include <math.h>

#define TPB 256
#define D 64

// ---------------------------------------------------------------------------
// Problem dims: N=129, B=128, D=64, NOUT=65, NIN=64, NMID=63
// x:          (129,128,2)      float32
// mps_input:  (64,64,64,2)     float32   Mi[n][l][r][i]
// mps_output: (65,64,64,2,2)   float32   Mo[n][l][r][i][j]
// out: 129 floats = out[0..127] (per-b) , out[128] = lnrm
// ---------------------------------------------------------------------------

__device__ __forceinline__ void zero4x4(float a[4][4]) {
#pragma unroll
    for (int i = 0; i < 4; ++i)
#pragma unroll
        for (int j = 0; j < 4; ++j) a[i][j] = 0.f;
}

// OUT tile store: OUT[(4ty+i)][4tx+j] = s*a[i][j], stride D, float4 stores.
__device__ __forceinline__ void store_tile(float* __restrict__ OUT,
                                           const float a[4][4], float s,
                                           int ty, int tx) {
#pragma unroll
    for (int i = 0; i < 4; ++i) {
        float4 v = make_float4(a[i][0] * s, a[i][1] * s, a[i][2] * s, a[i][3] * s);
        *(float4*)(OUT + (4 * ty + i) * D + 4 * tx) = v;
    }
}

// a[i][j] += sum_k P[k][4ty+i] * Q[k][4tx+j]   ("TN" form, conflict-free reads)
__device__ __forceinline__ void mm_tn_core(const float* __restrict__ P,
                                           const float* __restrict__ Q,
                                           float a[4][4], int ty, int tx) {
#pragma unroll 4
    for (int k = 0; k < D; ++k) {
        const float4 p = *(const float4*)(P + k * D + 4 * ty);
        const float4 q = *(const float4*)(Q + k * D + 4 * tx);
        a[0][0] += p.x * q.x; a[0][1] += p.x * q.y; a[0][2] += p.x * q.z; a[0][3] += p.x * q.w;
        a[1][0] += p.y * q.x; a[1][1] += p.y * q.y; a[1][2] += p.y * q.z; a[1][3] += p.y * q.w;
        a[2][0] += p.z * q.x; a[2][1] += p.z * q.y; a[2][2] += p.z * q.z; a[2][3] += p.z * q.w;
        a[3][0] += p.w * q.x; a[3][1] += p.w * q.y; a[3][2] += p.w * q.z; a[3][3] += p.w * q.w;
    }
}

// a[i][j] += sum_k P[4ty+i][k] * Q[k][4tx+j]   ("NN" form)
__device__ __forceinline__ void mm_nn_core(const float* __restrict__ P,
                                           const float* __restrict__ Q,
                                           float a[4][4], int ty, int tx) {
    for (int k = 0; k < D; k += 4) {
        float4 p0 = *(const float4*)(P + (4 * ty + 0) * D + k);
        float4 p1 = *(const float4*)(P + (4 * ty + 1) * D + k);
        float4 p2 = *(const float4*)(P + (4 * ty + 2) * D + k);
        float4 p3 = *(const float4*)(P + (4 * ty + 3) * D + k);
        float4 q0 = *(const float4*)(Q + (k + 0) * D + 4 * tx);
        float4 q1 = *(const float4*)(Q + (k + 1) * D + 4 * tx);
        float4 q2 = *(const float4*)(Q + (k + 2) * D + 4 * tx);
        float4 q3 = *(const float4*)(Q + (k + 3) * D + 4 * tx);
        a[0][0] += p0.x * q0.x + p0.y * q1.x + p0.z * q2.x + p0.w * q3.x;
        a[0][1] += p0.x * q0.y + p0.y * q1.y + p0.z * q2.y + p0.w * q3.y;
        a[0][2] += p0.x * q0.z + p0.y * q1.z + p0.z * q2.z + p0.w * q3.z;
        a[0][3] += p0.x * q0.w + p0.y * q1.w + p0.z * q2.w + p0.w * q3.w;
        a[1][0] += p1.x * q0.x + p1.y * q1.x + p1.z * q2.x + p1.w * q3.x;
        a[1][1] += p1.x * q0.y + p1.y * q1.y + p1.z * q2.y + p1.w * q3.y;
        a[1][2] += p1.x * q0.z + p1.y * q1.z + p1.z * q2.z + p1.w * q3.z;
        a[1][3] += p1.x * q0.w + p1.y * q1.w + p1.z * q2.w + p1.w * q3.w;
        a[2][0] += p2.x * q0.x + p2.y * q1.x + p2.z * q2.x + p2.w * q3.x;
        a[2][1] += p2.x * q0.y + p2.y * q1.y + p2.z * q2.y + p2.w * q3.y;
        a[2][2] += p2.x * q0.z + p2.y * q1.z + p2.z * q2.z + p2.w * q3.z;
        a[2][3] += p2.x * q0.w + p2.y * q1.w + p2.z * q2.w + p2.w * q3.w;
        a[3][0] += p3.x * q0.x + p3.y * q1.x + p3.z * q2.x + p3.w * q3.x;
        a[3][1] += p3.x * q0.y + p3.y * q1.y + p3.z * q2.y + p3.w * q3.y;
        a[3][2] += p3.x * q0.z + p3.y * q1.z + p3.z * q2.z + p3.w * q3.z;
        a[3][3] += p3.x * q0.w + p3.y * q1.w + p3.z * q2.w + p3.w * q3.w;
    }
}

__device__ __forceinline__ float block_amax(const float* __restrict__ S,
                                            float* scratch, int tid) {
    float m = 0.f;
#pragma unroll
    for (int j = 0; j < 16; ++j) m = fmaxf(m, fabsf(S[tid + j * TPB]));
#pragma unroll
    for (int off = 32; off > 0; off >>= 1) m = fmaxf(m, __shfl_down(m, off, 64));
    __syncthreads();
    if ((tid & 63) == 0) scratch[tid >> 6] = m;
    __syncthreads();
    m = fmaxf(fmaxf(scratch[0], scratch[1]), fmaxf(scratch[2], scratch[3]));
    __syncthreads();   // scratch slot reused right after; keep readers safe
    return m;
}

__global__ __launch_bounds__(TPB)
void mps_proj_kernel(const float* __restrict__ x,
                     const float* __restrict__ mi,
                     const float* __restrict__ mo,
                     float* __restrict__ out) {
    __shared__ float lds[4 * D * D];   // 64 KiB: S | P | Q | R
    float* S = lds;
    float* P = lds + 1 * D * D;
    float* Q = lds + 2 * D * D;
    float* R = lds + 3 * D * D;

    const int tid = threadIdx.x;
    const int ty = tid >> 4, tx = tid & 15;
    const float2* mi2 = (const float2*)mi;   // Mi[n][d][r][:] -> idx n*4096+d*64+r
    const float4* mo4 = (const float4*)mo;   // Mo[n][p][q][:][:] -> idx n*4096+p*64+q

    if (blockIdx.x < 128) {
        // =================== per-batch MPS scan, b = blockIdx.x ===================
        const int b = blockIdx.x;
        const float xa = x[b * 2 + 0], xb = x[b * 2 + 1];   // x[0,b,:]
        // A0[u][j] = sum_t x[0,b,t]*Mo[0][0][u][t][j]  -> P[u*2+j]
        if (tid < D) {
            float4 v = mo4[tid];
            P[tid * 2 + 0] = xa * v.x + xb * v.z;
            P[tid * 2 + 1] = xa * v.y + xb * v.w;
        }
        __syncthreads();
        // Al[u][d] = sum_j A0[u][j]*A0[d][j]
#pragma unroll
        for (int j = 0; j < 16; ++j) {
            int pos = tid + j * TPB;
            int u = pos >> 6, d = pos & 63;
            S[pos] = P[u * 2] * P[d * 2] + P[u * 2 + 1] * P[d * 2 + 1];
        }
        __syncthreads();

        float logsum = 0.f;
        float acc[4][4];

        for (int k = 0; k < 63; ++k) {
            const float amax = block_amax(S, Q, tid);
            logsum += logf(amax);
            const float inv = 1.f / amax;
            const float x1a = x[(2 * k + 1) * 256 + b * 2 + 0];
            const float x1b = x[(2 * k + 1) * 256 + b * 2 + 1];
            const float x0a = x[(2 * k + 2) * 256 + b * 2 + 0];
            const float x0b = x[(2 * k + 2) * 256 + b * 2 + 1];
            // Ain[d][r] = sum_t x1_t * Mi[k][d][r][t]  -> P
#pragma unroll
            for (int j = 0; j < 16; ++j) {
                int pos = tid + j * TPB;
                float2 m = mi2[k * 4096 + pos];
                P[pos] = x1a * m.x + x1b * m.y;
            }
            zero4x4(acc);
            for (int i = 0; i < 2; ++i) {
                // Xc[r][l] = sum_t x0_t * Mo[k+1][r][l][t][i]  -> Q
#pragma unroll
                for (int j = 0; j < 16; ++j) {
                    int pos = tid + j * TPB;
                    float4 m = mo4[(k + 1) * 4096 + pos];
                    Q[pos] = (i == 0) ? (x0a * m.x + x0b * m.z)
                                      : (x0a * m.y + x0b * m.w);
                }
                __syncthreads();
                // R = A_i : A[d][l] = sum_r Ain[d][r]*Xc[r][l]
                {
                    float t[4][4]; zero4x4(t);
                    mm_nn_core(P, Q, t, ty, tx);
                    store_tile(R, t, 1.f, ty, tx);
                }
                __syncthreads();
                // Q = T' : T'[u][l] = inv * sum_d S[d][u]*A[d][l]
                {
                    float t[4][4]; zero4x4(t);
                    mm_tn_core(S, R, t, ty, tx);
                    store_tile(Q, t, inv, ty, tx);
                }
                __syncthreads();
                // acc[l][r] += sum_u T'[u][l]*A[u][r]
                mm_tn_core(Q, R, acc, ty, tx);
                __syncthreads();
            }
            store_tile(S, acc, 1.f, ty, tx);
            __syncthreads();
        }

        // ------------- last step (l restricted to 0): quadratic form -------------
        {
            const float x1a = x[127 * 256 + b * 2 + 0];
            const float x1b = x[127 * 256 + b * 2 + 1];
            const float x0a = x[128 * 256 + b * 2 + 0];
            const float x0b = x[128 * 256 + b * 2 + 1];
#pragma unroll
            for (int j = 0; j < 16; ++j) {           // Ain63 -> P
                int pos = tid + j * TPB;
                float2 m = mi2[63 * 4096 + pos];
                P[pos] = x1a * m.x + x1b * m.y;
            }
            if (tid < D) {                            // w[r][i] = Xfull[64][r][0][i]
                float4 v = mo4[64 * 4096 + tid * 64];
                Q[tid * 2 + 0] = x0a * v.x + x0b * v.z;
                Q[tid * 2 + 1] = x0a * v.y + x0b * v.w;
            }
            __syncthreads();
            if (tid < 128) {                          // v[d][i] = sum_r Ain[d][r]*w[r][i]
                int d = tid >> 1, i = tid & 1;
                float s = 0.f;
                for (int r = 0; r < D; ++r) s += P[d * D + r] * Q[r * 2 + i];
                Q[256 + tid] = s;
            }
            __syncthreads();
            // val = sum_{d,u,i} v_i[d]*S[d][u]*v_i[u]   (amax of last step cancels)
            float part = 0.f;
#pragma unroll
            for (int j = 0; j < 16; ++j) {
                int pos = tid + j * TPB;
                int dd = pos >> 6, uu = pos & 63;
                part += S[pos] * (Q[256 + dd * 2] * Q[256 + uu * 2] +
                                  Q[256 + dd * 2 + 1] * Q[256 + uu * 2 + 1]);
            }
#pragma unroll
            for (int off = 32; off > 0; off >>= 1) part += __shfl_down(part, off, 64);
            __syncthreads();
            if ((tid & 63) == 0) R[tid >> 6] = part;
            __syncthreads();
            if (tid == 0) out[b] = logsum + logf(R[0] + R[1] + R[2] + R[3]);
        }
    } else {
        // ============================ lnrm scalar chain ============================
        // init: S[k][l] = sum_c Mo[0][0][k][c]*Mo[0][0][l][c]
        if (tid < D) {
            float4 v = mo4[tid];
            P[tid * 4 + 0] = v.x; P[tid * 4 + 1] = v.y;
            P[tid * 4 + 2] = v.z; P[tid * 4 + 3] = v.w;
        }
        __syncthreads();
#pragma unroll
        for (int j = 0; j < 16; ++j) {
            int pos = tid + j * TPB;
            int kk = pos >> 6, ll = pos & 63;
            S[pos] = P[kk * 4 + 0] * P[ll * 4 + 0] + P[kk * 4 + 1] * P[ll * 4 + 1] +
                     P[kk * 4 + 2] * P[ll * 4 + 2] + P[kk * 4 + 3] * P[ll * 4 + 3];
        }
        __syncthreads();

        float logsum = 0.f;
        float acc[4][4];
        for (int n = 0; n < 64; ++n) {
            // ---- contract_in with Mi[n]: M2 <- sum_t Mi_t^T (M2/a1) Mi_t ----
            const float a1 = block_amax(S, Q, tid);
            logsum += logf(a1);
            float inv = 1.f / a1;
            zero4x4(acc);
            for (int t = 0; t < 2; ++t) {
#pragma unroll
                for (int j = 0; j < 16; ++j) {        // R[d][k] = Mi[n][d][k][t]
                    int pos = tid + j * TPB;
                    float2 m = mi2[n * 4096 + pos];
                    R[pos] = t ? m.y : m.x;
                }
                __syncthreads();
                { float tt[4][4]; zero4x4(tt); mm_tn_core(S, R, tt, ty, tx);
                  store_tile(Q, tt, inv, ty, tx); }
                __syncthreads();
                mm_tn_core(Q, R, acc, ty, tx);
                __syncthreads();
            }
            store_tile(S, acc, 1.f, ty, tx);
            __syncthreads();
            // ---- contract_out with Mo[n+1]: M2 <- sum_c Mo_c^T (M2/a2) Mo_c ----
            const float a2 = block_amax(S, Q, tid);
            logsum += logf(a2);
            inv = 1.f / a2;
            zero4x4(acc);
            for (int c = 0; c < 4; ++c) {
#pragma unroll
                for (int j = 0; j < 16; ++j) {        // R[d][k] = Mo[n+1][d][k][c]
                    int pos = tid + j * TPB;
                    float4 m = mo4[(n + 1) * 4096 + pos];
                    R[pos] = (c == 0) ? m.x : (c == 1) ? m.y : (c == 2) ? m.z : m.w;
                }
                __syncthreads();
                { float tt[4][4]; zero4x4(tt); mm_tn_core(S, R, tt, ty, tx);
                  store_tile(Q, tt, inv, ty, tx); }
                __syncthreads();
                mm_tn_core(Q, R, acc, ty, tx);
                __syncthreads();
            }
            store_tile(S, acc, 1.f, ty, tx);
            __syncthreads();
        }
        if (tid == 0) out[128] = logsum + logf(S[0]);
    }
}

extern "C" void kernel_launch(void* const* d_in, const int* in_sizes, int n_in,
                              void* d_out, int out_size, void* d_ws, size_t ws_size,
                              hipStream_t stream) {
    (void)in_sizes; (void)n_in; (void)d_ws; (void)ws_size; (void)out_size;
    const float* x  = (const float*)d_in[0];
    const float* mi = (const float*)d_in[1];
    const float* mo = (const float*)d_in[2];
    float* out = (float*)d_out;
    hipLaunchKernelGGL(mps_proj_kernel, dim3(129), dim3(TPB), 0, stream,
                       x, mi, mo, out);
}

// Round 2
// 463.464 us; speedup vs baseline: 4.9330x; 4.9330x over previous
//
#include <hip/hip_runtime.h>
#include <math.h>

#define TPB 256

// ---------------------------------------------------------------------------
// N=129, B=128, D=64, NOUT=65, NIN=64, NMID=63
// x:          (129,128,2)  fp32     x[n*256 + b*2 + t]
// mps_input:  (64,64,64,2) fp32     mi2[n*4096 + l*64 + r] = (t0,t1)
// mps_output: (65,64,64,2,2) fp32   mo4[n*4096 + l*64 + r] = (00,01,10,11)
// out: 129 fp32 = out[0..127] per-batch, out[128] = lnrm
//
// Everything is the congruence primitive  S <- sum_g G^T S G  with S SYMMETRIC
// (PSD chain), done in bf16 MFMA 16x16x32. All bf16 LDS mats: stride 72
// (pad +8: 144B rows -> 16B-aligned ds_read_b128, 2-way-free banks).
// Storage conventions:  Sb[r][c] = S[r][c] (sym, == transposed)
//                       Gb[c][r] = G[r][c] (col-major -> both operand roles)
//                       Ub[c][r] = U[r][c]
// ---------------------------------------------------------------------------

typedef __attribute__((ext_vector_type(8))) short bf16x8;
typedef __attribute__((ext_vector_type(4))) float f32x4;
typedef unsigned short US;

#define LDM 72

__device__ __forceinline__ US f2b(float f) {
    union { float f; unsigned u; } v; v.f = f;
    return (US)((v.u + 0x7FFFu + ((v.u >> 16) & 1u)) >> 16);
}
__device__ __forceinline__ float bf2f(US h) {
    union { unsigned u; float f; } v; v.u = ((unsigned)h) << 16; return v.f;
}

// U = P(A-role, rows m) x Q(B-role, storage rows = matrix cols); write U
// transposed-bf16 into dstT (col-major storage).
__device__ __forceinline__ void mm_pair1(const US* __restrict__ Pa,
                                         const US* __restrict__ Qb,
                                         US* __restrict__ dstT,
                                         int R0, int lane) {
    const int m  = R0 + (lane & 15);
    const int q8 = ((lane >> 4) & 3) << 3;          // k-offset within 32-chunk
    const int rw = R0 + (((lane >> 4) & 3) << 2);   // C-layout row base (quad*4)
    bf16x8 a0 = *(const bf16x8*)(Pa + m * LDM + q8);
    bf16x8 a1 = *(const bf16x8*)(Pa + m * LDM + 32 + q8);
#pragma unroll
    for (int ct = 0; ct < 4; ++ct) {
        const int n = (ct << 4) + (lane & 15);
        bf16x8 b0 = *(const bf16x8*)(Qb + n * LDM + q8);
        bf16x8 b1 = *(const bf16x8*)(Qb + n * LDM + 32 + q8);
        f32x4 d = {0.f, 0.f, 0.f, 0.f};
        d = __builtin_amdgcn_mfma_f32_16x16x32_bf16(a0, b0, d, 0, 0, 0);
        d = __builtin_amdgcn_mfma_f32_16x16x32_bf16(a1, b1, d, 0, 0, 0);
        ushort4 wv;
        wv.x = f2b(d.x); wv.y = f2b(d.y); wv.z = f2b(d.z); wv.w = f2b(d.w);
        *(ushort4*)(dstT + n * LDM + rw) = wv;      // 8B aligned, ~4-way banks
    }
}

// acc += P(A-role) x Q(B-role)
__device__ __forceinline__ void mm_pair2(const US* __restrict__ Pa,
                                         const US* __restrict__ Qb,
                                         f32x4 acc[4], int R0, int lane) {
    const int m  = R0 + (lane & 15);
    const int q8 = ((lane >> 4) & 3) << 3;
    bf16x8 a0 = *(const bf16x8*)(Pa + m * LDM + q8);
    bf16x8 a1 = *(const bf16x8*)(Pa + m * LDM + 32 + q8);
#pragma unroll
    for (int ct = 0; ct < 4; ++ct) {
        const int n = (ct << 4) + (lane & 15);
        bf16x8 b0 = *(const bf16x8*)(Qb + n * LDM + q8);
        bf16x8 b1 = *(const bf16x8*)(Qb + n * LDM + 32 + q8);
        acc[ct] = __builtin_amdgcn_mfma_f32_16x16x32_bf16(a0, b0, acc[ct], 0, 0, 0);
        acc[ct] = __builtin_amdgcn_mfma_f32_16x16x32_bf16(a1, b1, acc[ct], 0, 0, 0);
    }
}

// Sb <- acc * scale (transposed store is fine: result symmetric)
__device__ __forceinline__ void storeS(US* __restrict__ Sb, const f32x4 acc[4],
                                       float scale, int R0, int lane) {
    const int rw = R0 + (((lane >> 4) & 3) << 2);
#pragma unroll
    for (int ct = 0; ct < 4; ++ct) {
        const int n = (ct << 4) + (lane & 15);
        ushort4 wv;
        wv.x = f2b(acc[ct].x * scale); wv.y = f2b(acc[ct].y * scale);
        wv.z = f2b(acc[ct].z * scale); wv.w = f2b(acc[ct].w * scale);
        *(ushort4*)(Sb + n * LDM + rw) = wv;
    }
}

__device__ __forceinline__ float block_amax4(const f32x4 acc[4], float* fsr, int tid) {
    float m = 0.f;
#pragma unroll
    for (int ct = 0; ct < 4; ++ct)
        m = fmaxf(m, fmaxf(fmaxf(fabsf(acc[ct].x), fabsf(acc[ct].y)),
                           fmaxf(fabsf(acc[ct].z), fabsf(acc[ct].w))));
#pragma unroll
    for (int off = 32; off; off >>= 1) m = fmaxf(m, __shfl_down(m, off, 64));
    __syncthreads();
    if ((tid & 63) == 0) fsr[tid >> 6] = m;
    __syncthreads();
    return fmaxf(fmaxf(fsr[0], fsr[1]), fmaxf(fsr[2], fsr[3]));
}

__global__ __launch_bounds__(TPB)
void mps_proj_kernel(const float* __restrict__ x,
                     const float* __restrict__ mi,
                     const float* __restrict__ mo,
                     float* __restrict__ out) {
    __shared__ __align__(16) US smem[6 * 64 * LDM];
    US* Sb = smem;
    US* Ub = smem + 64 * LDM;
    US* G0 = smem + 2 * 64 * LDM;
    US* G1 = smem + 3 * 64 * LDM;
    US* G2 = smem + 4 * 64 * LDM;
    US* G3 = smem + 5 * 64 * LDM;
    __shared__ float fsA[256];
    __shared__ float fsr[8];
    __shared__ float fsv[128];

    const int tid  = threadIdx.x;
    const int lane = tid & 63;
    const int R0   = (tid >> 6) << 4;
    // builder coordinates: thread writes storage rows rr, cols d0..d0+3
    const int rr = ((tid >> 6) << 4) + (tid & 15);
    const int qd = ((tid >> 4) & 3) << 2;

    const float2* mi2 = (const float2*)mi;
    const float4* mo4 = (const float4*)mo;

    f32x4 acc[4];

    if (blockIdx.x < 128) {
        // =================== per-batch MPS scan, b = blockIdx.x ==================
        const int b = blockIdx.x;
        const float xa = x[b * 2 + 0], xb = x[b * 2 + 1];
        // ---- init: A0[u][j], S0 = A0 A0^T, amax, scaled write ----
        if (tid < 64) {
            float4 v = mo4[tid];
            fsA[tid * 2 + 0] = xa * v.x + xb * v.z;
            fsA[tid * 2 + 1] = xa * v.y + xb * v.w;
        }
        __syncthreads();
        float vals[16]; float mloc = 0.f;
#pragma unroll
        for (int j = 0; j < 16; ++j) {
            int pos = tid + j * TPB; int u = pos >> 6, d = pos & 63;
            float s = fsA[u * 2] * fsA[d * 2] + fsA[u * 2 + 1] * fsA[d * 2 + 1];
            vals[j] = s; mloc = fmaxf(mloc, fabsf(s));
        }
#pragma unroll
        for (int off = 32; off; off >>= 1) mloc = fmaxf(mloc, __shfl_down(mloc, off, 64));
        if (lane == 0) fsr[tid >> 6] = mloc;
        __syncthreads();
        float amax = fmaxf(fmaxf(fsr[0], fsr[1]), fmaxf(fsr[2], fsr[3]));
        float logsum = logf(amax);
        float inv = 1.f / amax;
#pragma unroll
        for (int j = 0; j < 16; ++j) {
            int pos = tid + j * TPB;
            Sb[(pos >> 6) * LDM + (pos & 63)] = f2b(vals[j] * inv);
        }
        __syncthreads();

        for (int k = 0; k < 63; ++k) {
            const float x1a = x[(2 * k + 1) * 256 + b * 2 + 0];
            const float x1b = x[(2 * k + 1) * 256 + b * 2 + 1];
            const float x0a = x[(2 * k + 2) * 256 + b * 2 + 0];
            const float x0b = x[(2 * k + 2) * 256 + b * 2 + 1];
            // ---- build G0=Ain(k), G1=X0(k+1), G2=X1(k+1) (col-major bf16) ----
            {
                const float2* si = mi2 + k * 4096;
                const float4* so = mo4 + (k + 1) * 4096;
#pragma unroll
                for (int p = 0; p < 4; ++p) {
                    const int d0 = qd + (p << 4);
                    ushort4 w0, w1, w2;
#pragma unroll
                    for (int i = 0; i < 4; ++i) {
                        float2 mv = si[(d0 + i) * 64 + rr];
                        ((US*)&w0)[i] = f2b(x1a * mv.x + x1b * mv.y);
                        float4 ov = so[(d0 + i) * 64 + rr];
                        ((US*)&w1)[i] = f2b(x0a * ov.x + x0b * ov.z);
                        ((US*)&w2)[i] = f2b(x0a * ov.y + x0b * ov.w);
                    }
                    *(ushort4*)(G0 + rr * LDM + d0) = w0;
                    *(ushort4*)(G1 + rr * LDM + d0) = w1;
                    *(ushort4*)(G2 + rr * LDM + d0) = w2;
                }
            }
            __syncthreads();
            // ---- phase 1: S <- Ain^T S Ain  (unscaled) ----
            mm_pair1(Sb, G0, Ub, R0, lane);
            __syncthreads();
            acc[0] = acc[1] = acc[2] = acc[3] = (f32x4){0.f, 0.f, 0.f, 0.f};
            mm_pair2(G0, Ub, acc, R0, lane);
            __syncthreads();
            storeS(Sb, acc, 1.f, R0, lane);
            __syncthreads();
            // ---- phase 2: Al' = sum_t X_t^T S X_t ; amax ; scaled write ----
            acc[0] = acc[1] = acc[2] = acc[3] = (f32x4){0.f, 0.f, 0.f, 0.f};
            mm_pair1(Sb, G1, Ub, R0, lane);
            __syncthreads();
            mm_pair2(G1, Ub, acc, R0, lane);
            __syncthreads();
            mm_pair1(Sb, G2, Ub, R0, lane);
            __syncthreads();
            mm_pair2(G2, Ub, acc, R0, lane);
            amax = block_amax4(acc, fsr, tid);
            logsum += logf(amax);
            storeS(Sb, acc, 1.f / amax, R0, lane);
            // (no barrier: next-iter build writes G only; post-build barrier covers Sb)
        }

        // ---- last site: out[b] = logsum + log(sum_i v_i^T S v_i) ----
        {
            const float x1a = x[127 * 256 + b * 2 + 0];
            const float x1b = x[127 * 256 + b * 2 + 1];
            const float x0a = x[128 * 256 + b * 2 + 0];
            const float x0b = x[128 * 256 + b * 2 + 1];
            if (tid < 64) {                       // w[r][i]
                float4 v = mo4[64 * 4096 + tid * 64];
                fsA[tid * 2 + 0] = x0a * v.x + x0b * v.z;
                fsA[tid * 2 + 1] = x0a * v.y + x0b * v.w;
            }
            {                                     // Ain63 -> G0 (col-major bf16)
                const float2* si = mi2 + 63 * 4096;
#pragma unroll
                for (int p = 0; p < 4; ++p) {
                    const int d0 = qd + (p << 4);
                    ushort4 w0;
#pragma unroll
                    for (int i = 0; i < 4; ++i) {
                        float2 mv = si[(d0 + i) * 64 + rr];
                        ((US*)&w0)[i] = f2b(x1a * mv.x + x1b * mv.y);
                    }
                    *(ushort4*)(G0 + rr * LDM + d0) = w0;
                }
            }
            __syncthreads();
            if (tid < 128) {                      // v[d][i] = sum_r Ain[d][r] w[r][i]
                int dd = tid >> 1, ii = tid & 1;
                float s = 0.f;
                for (int r = 0; r < 64; ++r) s += bf2f(G0[r * LDM + dd]) * fsA[r * 2 + ii];
                fsv[tid] = s;
            }
            __syncthreads();
            float part = 0.f;
#pragma unroll
            for (int j = 0; j < 16; ++j) {
                int pos = tid + j * TPB; int dd = pos >> 6, uu = pos & 63;
                part += bf2f(Sb[dd * LDM + uu]) *
                        (fsv[dd * 2] * fsv[uu * 2] + fsv[dd * 2 + 1] * fsv[uu * 2 + 1]);
            }
#pragma unroll
            for (int off = 32; off; off >>= 1) part += __shfl_down(part, off, 64);
            if (lane == 0) fsr[tid >> 6] = part;
            __syncthreads();
            if (tid == 0) out[b] = logsum + logf(fsr[0] + fsr[1] + fsr[2] + fsr[3]);
        }
    } else {
        // ============================ lnrm scalar chain ==========================
        // init: Aln[k][l] = dot4(Mo0[0][k], Mo0[0][l]); amax; scaled write
        if (tid < 64) {
            float4 v = mo4[tid];
            fsA[tid * 4 + 0] = v.x; fsA[tid * 4 + 1] = v.y;
            fsA[tid * 4 + 2] = v.z; fsA[tid * 4 + 3] = v.w;
        }
        __syncthreads();
        float vals[16]; float mloc = 0.f;
#pragma unroll
        for (int j = 0; j < 16; ++j) {
            int pos = tid + j * TPB; int kk = pos >> 6, ll = pos & 63;
            float s = fsA[kk * 4 + 0] * fsA[ll * 4 + 0] + fsA[kk * 4 + 1] * fsA[ll * 4 + 1] +
                      fsA[kk * 4 + 2] * fsA[ll * 4 + 2] + fsA[kk * 4 + 3] * fsA[ll * 4 + 3];
            vals[j] = s; mloc = fmaxf(mloc, fabsf(s));
        }
#pragma unroll
        for (int off = 32; off; off >>= 1) mloc = fmaxf(mloc, __shfl_down(mloc, off, 64));
        if (lane == 0) fsr[tid >> 6] = mloc;
        __syncthreads();
        float amax = fmaxf(fmaxf(fsr[0], fsr[1]), fmaxf(fsr[2], fsr[3]));
        float logsum = logf(amax);
        float inv = 1.f / amax;
#pragma unroll
        for (int j = 0; j < 16; ++j) {
            int pos = tid + j * TPB;
            Sb[(pos >> 6) * LDM + (pos & 63)] = f2b(vals[j] * inv);
        }
        __syncthreads();

        US* Gin[2]  = {G0, G1};
        US* Gout[4] = {G0, G1, G2, G3};
        for (int n = 0; n < 64; ++n) {
            // ---- contract_in gens: G0=Mi[:, :, 0], G1=Mi[:, :, 1] ----
            {
                const float2* si = mi2 + n * 4096;
#pragma unroll
                for (int p = 0; p < 4; ++p) {
                    const int d0 = qd + (p << 4);
                    ushort4 w0, w1;
#pragma unroll
                    for (int i = 0; i < 4; ++i) {
                        float2 mv = si[(d0 + i) * 64 + rr];
                        ((US*)&w0)[i] = f2b(mv.x);
                        ((US*)&w1)[i] = f2b(mv.y);
                    }
                    *(ushort4*)(G0 + rr * LDM + d0) = w0;
                    *(ushort4*)(G1 + rr * LDM + d0) = w1;
                }
            }
            __syncthreads();
            acc[0] = acc[1] = acc[2] = acc[3] = (f32x4){0.f, 0.f, 0.f, 0.f};
#pragma unroll
            for (int g = 0; g < 2; ++g) {
                mm_pair1(Sb, Gin[g], Ub, R0, lane);
                __syncthreads();
                mm_pair2(Gin[g], Ub, acc, R0, lane);
                __syncthreads();
            }
            amax = block_amax4(acc, fsr, tid);
            logsum += logf(amax);
            storeS(Sb, acc, 1.f / amax, R0, lane);
            __syncthreads();
            // ---- contract_out gens: Mo[n+1][:, :, c] for c in 4 ----
            {
                const float4* so = mo4 + (n + 1) * 4096;
#pragma unroll
                for (int p = 0; p < 4; ++p) {
                    const int d0 = qd + (p << 4);
                    ushort4 w0, w1, w2, w3;
#pragma unroll
                    for (int i = 0; i < 4; ++i) {
                        float4 ov = so[(d0 + i) * 64 + rr];
                        ((US*)&w0)[i] = f2b(ov.x); ((US*)&w1)[i] = f2b(ov.y);
                        ((US*)&w2)[i] = f2b(ov.z); ((US*)&w3)[i] = f2b(ov.w);
                    }
                    *(ushort4*)(G0 + rr * LDM + d0) = w0;
                    *(ushort4*)(G1 + rr * LDM + d0) = w1;
                    *(ushort4*)(G2 + rr * LDM + d0) = w2;
                    *(ushort4*)(G3 + rr * LDM + d0) = w3;
                }
            }
            __syncthreads();
            acc[0] = acc[1] = acc[2] = acc[3] = (f32x4){0.f, 0.f, 0.f, 0.f};
#pragma unroll
            for (int g = 0; g < 4; ++g) {
                mm_pair1(Sb, Gout[g], Ub, R0, lane);
                __syncthreads();
                mm_pair2(Gout[g], Ub, acc, R0, lane);
                __syncthreads();
            }
            if (n < 63) {
                amax = block_amax4(acc, fsr, tid);
                logsum += logf(amax);
                storeS(Sb, acc, 1.f / amax, R0, lane);
                __syncthreads();
            } else {
                // AlN[0][0] lives at wave0 (R0=0), ct=0, lane 0, reg 0
                if (tid == 0) out[128] = logsum + logf(acc[0].x);
            }
        }
    }
}

extern "C" void kernel_launch(void* const* d_in, const int* in_sizes, int n_in,
                              void* d_out, int out_size, void* d_ws, size_t ws_size,
                              hipStream_t stream) {
    (void)in_sizes; (void)n_in; (void)d_ws; (void)ws_size; (void)out_size;
    const float* x  = (const float*)d_in[0];
    const float* mi = (const float*)d_in[1];
    const float* mo = (const float*)d_in[2];
    float* out = (float*)d_out;
    hipLaunchKernelGGL(mps_proj_kernel, dim3(129), dim3(TPB), 0, stream,
                       x, mi, mo, out);
}

// Round 4
// 349.304 us; speedup vs baseline: 6.5453x; 1.3268x over previous
//
#include <hip/hip_runtime.h>
#include <math.h>

#define TPB 512
#define LDM 72   // bf16 row stride: 144 B -> 16B-aligned b128, conflict-free

// ---------------------------------------------------------------------------
// N=129, B=128, D=64, NOUT=65, NIN=64, NMID=63
// x:          (129,128,2)  fp32     x[n*256 + b*2 + t]
// mps_input:  (64,64,64,2) fp32     mi2[n*4096 + l*64 + r] = (t0,t1)
// mps_output: (65,64,64,2,2) fp32   mo4[n*4096 + l*64 + r] = (00,01,10,11)
// out: 129 fp32 = out[0..127] per-batch, out[128] = lnrm
//
// Congruence primitive S <- sum_g G^T S G (S symmetric) in bf16 MFMA
// 16x16x32, tiled as 32x32 output units per wave (a/b frags reused in regs).
// Storage: Sb[r][c]=S[r][c] (sym), Gb/Ub col-major (storage row = matrix col).
// 512 threads = 8 waves. LDS buffers addressed by computed offset (pointer
// arrays into LDS miscompile on gfx950: addrspacecast static-init error).
// ---------------------------------------------------------------------------

typedef __attribute__((ext_vector_type(8))) short bf16x8;
typedef __attribute__((ext_vector_type(4))) float f32x4;
typedef unsigned short US;

__device__ __forceinline__ US f2b(float f) {
    union { float f; unsigned u; } v; v.f = f;
    return (US)((v.u + 0x7FFFu + ((v.u >> 16) & 1u)) >> 16);
}
__device__ __forceinline__ float bf2f(US h) {
    union { unsigned u; float f; } v; v.u = ((unsigned)h) << 16; return v.f;
}

// 32x32 unit of U = P(A-role, rows R0..R0+32) x Q(B-role col-major, cols C0..C0+32)
// result written transposed-bf16 into dstT (col-major storage).
__device__ __forceinline__ void unitA(const US* P, const US* Q, US* dstT,
                                      int R0, int C0, int lane) {
    const int ml = lane & 15;
    const int q8 = (lane >> 4) << 3;
    bf16x8 a[2][2];
#pragma unroll
    for (int rt = 0; rt < 2; ++rt) {
        const US* base = P + (R0 + 16 * rt + ml) * LDM + q8;
        a[rt][0] = *(const bf16x8*)(base);
        a[rt][1] = *(const bf16x8*)(base + 32);
    }
#pragma unroll
    for (int ct = 0; ct < 2; ++ct) {
        const US* qb = Q + (C0 + 16 * ct + ml) * LDM + q8;
        bf16x8 b0 = *(const bf16x8*)(qb);
        bf16x8 b1 = *(const bf16x8*)(qb + 32);
        US* dcol = dstT + (C0 + 16 * ct + ml) * LDM + R0 + (q8 >> 1);
#pragma unroll
        for (int rt = 0; rt < 2; ++rt) {
            f32x4 d = {0.f, 0.f, 0.f, 0.f};
            d = __builtin_amdgcn_mfma_f32_16x16x32_bf16(a[rt][0], b0, d, 0, 0, 0);
            d = __builtin_amdgcn_mfma_f32_16x16x32_bf16(a[rt][1], b1, d, 0, 0, 0);
            ushort4 wv;
            wv.x = f2b(d.x); wv.y = f2b(d.y); wv.z = f2b(d.z); wv.w = f2b(d.w);
            *(ushort4*)(dcol + 16 * rt) = wv;
        }
    }
}

// acc[2][2] += 32x32 unit of G^T U  (G,U col-major storage)
__device__ __forceinline__ void unitB(const US* Gm, const US* Um,
                                      f32x4 acc[2][2], int R0, int C0, int lane) {
    const int ml = lane & 15;
    const int q8 = (lane >> 4) << 3;
    bf16x8 a[2][2];
#pragma unroll
    for (int rt = 0; rt < 2; ++rt) {
        const US* base = Gm + (R0 + 16 * rt + ml) * LDM + q8;
        a[rt][0] = *(const bf16x8*)(base);
        a[rt][1] = *(const bf16x8*)(base + 32);
    }
#pragma unroll
    for (int ct = 0; ct < 2; ++ct) {
        const US* qb = Um + (C0 + 16 * ct + ml) * LDM + q8;
        bf16x8 b0 = *(const bf16x8*)(qb);
        bf16x8 b1 = *(const bf16x8*)(qb + 32);
#pragma unroll
        for (int rt = 0; rt < 2; ++rt) {
            acc[rt][ct] = __builtin_amdgcn_mfma_f32_16x16x32_bf16(a[rt][0], b0, acc[rt][ct], 0, 0, 0);
            acc[rt][ct] = __builtin_amdgcn_mfma_f32_16x16x32_bf16(a[rt][1], b1, acc[rt][ct], 0, 0, 0);
        }
    }
}

__device__ __forceinline__ void storeS32(US* Sb, const f32x4 acc[2][2], float s,
                                         int R0, int C0, int lane) {
    const int ml = lane & 15;
    const int q4 = (lane >> 4) << 2;
#pragma unroll
    for (int ct = 0; ct < 2; ++ct)
#pragma unroll
        for (int rt = 0; rt < 2; ++rt) {
            ushort4 wv;
            wv.x = f2b(acc[rt][ct].x * s); wv.y = f2b(acc[rt][ct].y * s);
            wv.z = f2b(acc[rt][ct].z * s); wv.w = f2b(acc[rt][ct].w * s);
            *(ushort4*)(Sb + (C0 + 16 * ct + ml) * LDM + R0 + 16 * rt + q4) = wv;
        }
}

__device__ __forceinline__ float wavemax16(const f32x4 acc[2][2]) {
    float m = 0.f;
#pragma unroll
    for (int rt = 0; rt < 2; ++rt)
#pragma unroll
        for (int ct = 0; ct < 2; ++ct)
            m = fmaxf(m, fmaxf(fmaxf(fabsf(acc[rt][ct].x), fabsf(acc[rt][ct].y)),
                               fmaxf(fabsf(acc[rt][ct].z), fabsf(acc[rt][ct].w))));
#pragma unroll
    for (int off = 32; off; off >>= 1) m = fmaxf(m, __shfl_down(m, off, 64));
    return m;
}

__global__ __launch_bounds__(TPB)
void mps_proj_kernel(const float* __restrict__ x,
                     const float* __restrict__ mi,
                     const float* __restrict__ mo,
                     float* __restrict__ out) {
    __shared__ __align__(16) US smem[9 * 64 * LDM];   // S | U0..U3 | G0..G3
    US* const Sb = smem;
#define UsP(g) (smem + (1 + (g)) * 64 * LDM)
#define GsP(g) (smem + (5 + (g)) * 64 * LDM)
    __shared__ float fsA[256];
    __shared__ float fsr[8];
    __shared__ float fsv[128];

    const int tid  = threadIdx.x;
    const int lane = tid & 63;
    const int w    = tid >> 6;                 // wave id 0..7
    const int rr   = tid & 63;                 // builder storage row
    const int R0   = ((w >> 1) & 1) * 32;      // B-phase unit coords (w<4)
    const int C0   = (w & 1) * 32;

    const float2* mi2 = (const float2*)mi;
    const float4* mo4 = (const float4*)mo;

    if (blockIdx.x < 128) {
        // =================== per-batch MPS scan, b = blockIdx.x ==================
        const int b = blockIdx.x;
        const float xa = x[b * 2 + 0], xb = x[b * 2 + 1];
        if (tid < 64) {
            float4 v = mo4[tid];
            fsA[tid * 2 + 0] = xa * v.x + xb * v.z;
            fsA[tid * 2 + 1] = xa * v.y + xb * v.w;
        }
        __syncthreads();
        float vals[8]; float mloc = 0.f;
#pragma unroll
        for (int j = 0; j < 8; ++j) {
            int pos = tid + j * TPB; int u = pos >> 6, d = pos & 63;
            float s = fsA[u * 2] * fsA[d * 2] + fsA[u * 2 + 1] * fsA[d * 2 + 1];
            vals[j] = s; mloc = fmaxf(mloc, fabsf(s));
        }
#pragma unroll
        for (int off = 32; off; off >>= 1) mloc = fmaxf(mloc, __shfl_down(mloc, off, 64));
        if (lane == 0) fsr[w] = mloc;
        __syncthreads();
        float amax = fsr[0];
#pragma unroll
        for (int i = 1; i < 8; ++i) amax = fmaxf(amax, fsr[i]);
        float logsum = logf(amax);
        float inv = 1.f / amax;
#pragma unroll
        for (int j = 0; j < 8; ++j) {
            int pos = tid + j * TPB;
            Sb[(pos >> 6) * LDM + (pos & 63)] = f2b(vals[j] * inv);
        }
        __syncthreads();

        for (int k = 0; k < 63; ++k) {
            // R1: build G0=Ain(k), G1=X0(k+1), G2=X1(k+1) (col-major bf16)
            const float x1a = x[(2 * k + 1) * 256 + b * 2 + 0];
            const float x1b = x[(2 * k + 1) * 256 + b * 2 + 1];
            const float x0a = x[(2 * k + 2) * 256 + b * 2 + 0];
            const float x0b = x[(2 * k + 2) * 256 + b * 2 + 1];
            {
                const float2* si = mi2 + k * 4096;
                const float4* so = mo4 + (k + 1) * 4096;
#pragma unroll
                for (int p = 0; p < 2; ++p) {
                    const int d0 = (w << 2) + (p << 5);
                    ushort4 w0, w1, w2;
#pragma unroll
                    for (int i = 0; i < 4; ++i) {
                        float2 mv = si[(d0 + i) * 64 + rr];
                        ((US*)&w0)[i] = f2b(x1a * mv.x + x1b * mv.y);
                        float4 ov = so[(d0 + i) * 64 + rr];
                        ((US*)&w1)[i] = f2b(x0a * ov.x + x0b * ov.z);
                        ((US*)&w2)[i] = f2b(x0a * ov.y + x0b * ov.w);
                    }
                    *(ushort4*)(GsP(0) + rr * LDM + d0) = w0;
                    *(ushort4*)(GsP(1) + rr * LDM + d0) = w1;
                    *(ushort4*)(GsP(2) + rr * LDM + d0) = w2;
                }
            }
            __syncthreads();                                   // s1
            // R2: U0 = S * G0   (4 units, waves 0-3)
            if (w < 4) unitA(Sb, GsP(0), UsP(0), R0, C0, lane);
            __syncthreads();                                   // s2
            // R3: S <- G0^T U0 (unscaled)
            f32x4 acc[2][2];
            if (w < 4) {
                acc[0][0] = acc[0][1] = acc[1][0] = acc[1][1] = (f32x4){0.f, 0.f, 0.f, 0.f};
                unitB(GsP(0), UsP(0), acc, R0, C0, lane);
                storeS32(Sb, acc, 1.f, R0, C0, lane);
            }
            __syncthreads();                                   // s3
            // R4: U_t = S * X_t   (8 units, all waves)
            {
                const int g = w >> 2, t = w & 3;
                unitA(Sb, GsP(1 + g), UsP(g), ((t >> 1) & 1) * 32, (t & 1) * 32, lane);
            }
            __syncthreads();                                   // s4
            // R5: acc = sum_t X_t^T U_t ; wave max
            if (w < 4) {
                acc[0][0] = acc[0][1] = acc[1][0] = acc[1][1] = (f32x4){0.f, 0.f, 0.f, 0.f};
                unitB(GsP(1), UsP(0), acc, R0, C0, lane);
                unitB(GsP(2), UsP(1), acc, R0, C0, lane);
                float m = wavemax16(acc);
                if (lane == 0) fsr[w] = m;
            }
            __syncthreads();                                   // s5
            // R6: amax, log, scaled store
            amax = fmaxf(fmaxf(fsr[0], fsr[1]), fmaxf(fsr[2], fsr[3]));
            logsum += logf(amax);
            if (w < 4) storeS32(Sb, acc, 1.f / amax, R0, C0, lane);
            __syncthreads();                                   // s6 (Sb write vs next build read safety)
        }

        // ---- last site: out[b] = logsum + log(sum_i v_i^T S v_i) ----
        {
            const float x1a = x[127 * 256 + b * 2 + 0];
            const float x1b = x[127 * 256 + b * 2 + 1];
            const float x0a = x[128 * 256 + b * 2 + 0];
            const float x0b = x[128 * 256 + b * 2 + 1];
            if (tid < 64) {                       // w[r][i]
                float4 v = mo4[64 * 4096 + tid * 64];
                fsA[tid * 2 + 0] = x0a * v.x + x0b * v.z;
                fsA[tid * 2 + 1] = x0a * v.y + x0b * v.w;
            }
            {                                     // Ain63 -> G0 (col-major bf16)
                const float2* si = mi2 + 63 * 4096;
#pragma unroll
                for (int p = 0; p < 2; ++p) {
                    const int d0 = (w << 2) + (p << 5);
                    ushort4 w0;
#pragma unroll
                    for (int i = 0; i < 4; ++i) {
                        float2 mv = si[(d0 + i) * 64 + rr];
                        ((US*)&w0)[i] = f2b(x1a * mv.x + x1b * mv.y);
                    }
                    *(ushort4*)(GsP(0) + rr * LDM + d0) = w0;
                }
            }
            __syncthreads();
            if (tid < 128) {                      // v[d][i] = sum_r Ain[d][r] w[r][i]
                int dd = tid >> 1, ii = tid & 1;
                float s = 0.f;
                for (int r = 0; r < 64; ++r) s += bf2f(GsP(0)[r * LDM + dd]) * fsA[r * 2 + ii];
                fsv[tid] = s;
            }
            __syncthreads();
            float part = 0.f;
#pragma unroll
            for (int j = 0; j < 8; ++j) {
                int pos = tid + j * TPB; int dd = pos >> 6, uu = pos & 63;
                part += bf2f(Sb[dd * LDM + uu]) *
                        (fsv[dd * 2] * fsv[uu * 2] + fsv[dd * 2 + 1] * fsv[uu * 2 + 1]);
            }
#pragma unroll
            for (int off = 32; off; off >>= 1) part += __shfl_down(part, off, 64);
            if (lane == 0) fsr[w] = part;
            __syncthreads();
            if (tid == 0) {
                float t = 0.f;
#pragma unroll
                for (int i = 0; i < 8; ++i) t += fsr[i];
                out[b] = logsum + logf(t);
            }
        }
    } else {
        // ============================ lnrm scalar chain ==========================
        if (tid < 64) {
            float4 v = mo4[tid];
            fsA[tid * 4 + 0] = v.x; fsA[tid * 4 + 1] = v.y;
            fsA[tid * 4 + 2] = v.z; fsA[tid * 4 + 3] = v.w;
        }
        __syncthreads();
        float vals[8]; float mloc = 0.f;
#pragma unroll
        for (int j = 0; j < 8; ++j) {
            int pos = tid + j * TPB; int kk = pos >> 6, ll = pos & 63;
            float s = fsA[kk * 4 + 0] * fsA[ll * 4 + 0] + fsA[kk * 4 + 1] * fsA[ll * 4 + 1] +
                      fsA[kk * 4 + 2] * fsA[ll * 4 + 2] + fsA[kk * 4 + 3] * fsA[ll * 4 + 3];
            vals[j] = s; mloc = fmaxf(mloc, fabsf(s));
        }
#pragma unroll
        for (int off = 32; off; off >>= 1) mloc = fmaxf(mloc, __shfl_down(mloc, off, 64));
        if (lane == 0) fsr[w] = mloc;
        __syncthreads();
        float amax = fsr[0];
#pragma unroll
        for (int i = 1; i < 8; ++i) amax = fmaxf(amax, fsr[i]);
        float logsum = logf(amax);
        float inv = 1.f / amax;
#pragma unroll
        for (int j = 0; j < 8; ++j) {
            int pos = tid + j * TPB;
            Sb[(pos >> 6) * LDM + (pos & 63)] = f2b(vals[j] * inv);
        }
        __syncthreads();

        for (int n = 0; n < 64; ++n) {
            // R1: build in-gens G0,G1 from mi[n]
            {
                const float2* si = mi2 + n * 4096;
#pragma unroll
                for (int p = 0; p < 2; ++p) {
                    const int d0 = (w << 2) + (p << 5);
                    ushort4 w0, w1;
#pragma unroll
                    for (int i = 0; i < 4; ++i) {
                        float2 mv = si[(d0 + i) * 64 + rr];
                        ((US*)&w0)[i] = f2b(mv.x);
                        ((US*)&w1)[i] = f2b(mv.y);
                    }
                    *(ushort4*)(GsP(0) + rr * LDM + d0) = w0;
                    *(ushort4*)(GsP(1) + rr * LDM + d0) = w1;
                }
            }
            __syncthreads();                                   // s1
            // R2: inA — U_g = S*G_g (8 units, all waves)
            {
                const int g = w >> 2, t = w & 3;
                unitA(Sb, GsP(g), UsP(g), ((t >> 1) & 1) * 32, (t & 1) * 32, lane);
            }
            __syncthreads();                                   // s2
            // R3: inB — acc = sum_g G_g^T U_g ; wave max
            f32x4 acc[2][2];
            if (w < 4) {
                acc[0][0] = acc[0][1] = acc[1][0] = acc[1][1] = (f32x4){0.f, 0.f, 0.f, 0.f};
                unitB(GsP(0), UsP(0), acc, R0, C0, lane);
                unitB(GsP(1), UsP(1), acc, R0, C0, lane);
                float m = wavemax16(acc);
                if (lane == 0) fsr[w] = m;
            }
            __syncthreads();                                   // s3
            // R4: a1, scaled store
            {
                float a1 = fmaxf(fmaxf(fsr[0], fsr[1]), fmaxf(fsr[2], fsr[3]));
                logsum += logf(a1);
                if (w < 4) storeS32(Sb, acc, 1.f / a1, R0, C0, lane);
            }
            __syncthreads();                                   // s4 (Sb settled)
            // R5: build out-gens G0..G3 from mo[n+1]
            {
                const float4* so = mo4 + (n + 1) * 4096;
#pragma unroll
                for (int p = 0; p < 2; ++p) {
                    const int d0 = (w << 2) + (p << 5);
                    ushort4 w0, w1, w2, w3;
#pragma unroll
                    for (int i = 0; i < 4; ++i) {
                        float4 ov = so[(d0 + i) * 64 + rr];
                        ((US*)&w0)[i] = f2b(ov.x); ((US*)&w1)[i] = f2b(ov.y);
                        ((US*)&w2)[i] = f2b(ov.z); ((US*)&w3)[i] = f2b(ov.w);
                    }
                    *(ushort4*)(GsP(0) + rr * LDM + d0) = w0;
                    *(ushort4*)(GsP(1) + rr * LDM + d0) = w1;
                    *(ushort4*)(GsP(2) + rr * LDM + d0) = w2;
                    *(ushort4*)(GsP(3) + rr * LDM + d0) = w3;
                }
            }
            __syncthreads();                                   // s5
            // R6: outA — U_g = S*G_g, 16 units on 8 waves
#pragma unroll
            for (int uu = 0; uu < 2; ++uu) {
                const int u = w + uu * 8;
                const int g = u >> 2, t = u & 3;
                unitA(Sb, GsP(g), UsP(g), ((t >> 1) & 1) * 32, (t & 1) * 32, lane);
            }
            __syncthreads();                                   // s6
            // R7: outB — acc = sum_g G_g^T U_g ; wave max
            if (w < 4) {
                acc[0][0] = acc[0][1] = acc[1][0] = acc[1][1] = (f32x4){0.f, 0.f, 0.f, 0.f};
#pragma unroll
                for (int g = 0; g < 4; ++g) unitB(GsP(g), UsP(g), acc, R0, C0, lane);
                float m = wavemax16(acc);
                if (lane == 0) fsr[w] = m;
            }
            __syncthreads();                                   // s7
            // R8: a2, log, store (or final output)
            {
                float a2 = fmaxf(fmaxf(fsr[0], fsr[1]), fmaxf(fsr[2], fsr[3]));
                logsum += logf(a2);
                if (n < 63) {
                    if (w < 4) storeS32(Sb, acc, 1.f / a2, R0, C0, lane);
                } else {
                    // S[0][0] sits in wave0 unit (R0=0,C0=0), lane 0, acc[0][0].x
                    if (tid == 0) out[128] = logsum + logf(acc[0][0].x / a2);
                }
            }
            __syncthreads();                                   // s8
        }
    }
#undef UsP
#undef GsP
}

extern "C" void kernel_launch(void* const* d_in, const int* in_sizes, int n_in,
                              void* d_out, int out_size, void* d_ws, size_t ws_size,
                              hipStream_t stream) {
    (void)in_sizes; (void)n_in; (void)d_ws; (void)ws_size; (void)out_size;
    const float* x  = (const float*)d_in[0];
    const float* mi = (const float*)d_in[1];
    const float* mo = (const float*)d_in[2];
    float* out = (float*)d_out;
    hipLaunchKernelGGL(mps_proj_kernel, dim3(129), dim3(TPB), 0, stream,
                       x, mi, mo, out);
}